// Round 9
// baseline (3591.868 us; speedup 1.0000x reference)
//
#include <hip/hip_runtime.h>
#include <stdint.h>

typedef __bf16 bf16_t;
typedef __bf16 bf16x8 __attribute__((ext_vector_type(8)));
typedef float floatx16 __attribute__((ext_vector_type(16)));
typedef unsigned int u32;
typedef unsigned long long u64;

#define NPROD 64   // Gx producer WGs
#define H1R   16   // h1 ring depth
#define FP    32   // flag padding: 32 u32 = 128 B per flag (one LLC line each)

struct KParams {
  const int* tok;
  const float* emb;
  const float* W1[4]; const float* b1[4];
  const float* W2[4]; const float* b2[4];
  const float* Wd; const float* bd; const float* Wout; const float* bout;
  float* out;
  uint16_t* h1;      // ring: H1R x [64][256] bf16
  uint16_t* h2;      // ring: 2   x [64][256] bf16
  u32* fl0;          // 16 flags, 128B-padded
  u32* fl1;          // 32 flags, 128B-padded
  u32* fl0g;         // 16 flags, 128B-padded (producer-only mirror of fl0)
  u32* pflags;       // 512 flags, 128B-padded (producers -> L0)
  float* dstage;     // [64][128] fp32
  bf16_t* w1bf;      // [20][1024][16] fragment-ordered x-weights (bf16)
  float* gx;         // ring: R slabs, lane-linear [ct(32)][mh(2)][lane(64)][e(16)] fp32
  int R;
};

__device__ __forceinline__ float sigf(float x) { return 1.f / (1.f + __expf(-x)); }
__device__ __forceinline__ float tanhf_fast(float x) { return 1.f - 2.f / (__expf(2.f * x) + 1.f); }

__device__ __forceinline__ u32 pack2(float a, float b) {
  uint16_t x = __builtin_bit_cast(uint16_t, (bf16_t)a);
  uint16_t y = __builtin_bit_cast(uint16_t, (bf16_t)b);
  return ((u32)y << 16) | (u32)x;
}
__device__ __forceinline__ float2 u2f2(u64 v) { union { u64 u; float2 f; } x; x.u = v; return x.f; }
__device__ __forceinline__ u64 f22u(float a, float b) { union { u64 u; float2 f; } x; x.f = make_float2(a, b); return x.u; }
__device__ __forceinline__ bf16x8 mk_frag(u64 lo, u64 hi) {
  union { u64 u[2]; bf16x8 v; } x; x.u[0] = lo; x.u[1] = hi; return x.v;
}

// relaxed agent-scope ops: bypass L1/L2, coherent at LLC
__device__ __forceinline__ u32  ald32(const u32* p) { return __hip_atomic_load(p, __ATOMIC_RELAXED, __HIP_MEMORY_SCOPE_AGENT); }
__device__ __forceinline__ void ast32(u32* p, u32 v) { __hip_atomic_store(p, v, __ATOMIC_RELAXED, __HIP_MEMORY_SCOPE_AGENT); }
__device__ __forceinline__ u64  ald64(const u64* p) { return __hip_atomic_load(p, __ATOMIC_RELAXED, __HIP_MEMORY_SCOPE_AGENT); }
__device__ __forceinline__ void ast64(u64* p, u64 v) { __hip_atomic_store(p, v, __ATOMIC_RELAXED, __HIP_MEMORY_SCOPE_AGENT); }

// Wave-parallel dataflow wait (wave 0 only, then __syncthreads):
// lanes [0,NA): fa[lane*FP]>=na; [NA,NA+NB): fb[(lane-NA)*FP]>=nb; rest: *pc>=nc.
template<int NA, int NB>
__device__ __forceinline__ void waitcond(const u32* fa, u32 na, const u32* fb, u32 nb,
                                         const u32* pc, u32 nc) {
  const int lane = threadIdx.x & 63;
  const u32* ap; u32 need;
  if (lane < NA)           { ap = fa + lane * FP;        need = na; }
  else if (lane < NA + NB) { ap = fb + (lane - NA) * FP; need = nb; }
  else                     { ap = pc;                    need = nc; }
  while (!__all(ald32(ap) >= need)) {}
  __atomic_signal_fence(__ATOMIC_ACQUIRE);
}

// producer-side wait on the 16-flag mirror (keeps poll traffic off fl0's lines)
__device__ __forceinline__ void waitg16(const u32* fa, u32 na) {
  const int lane = threadIdx.x & 63;
  const u32* ap = fa + (lane & 15) * FP;
  while (!__all(ald32(ap) >= na)) {}
  __atomic_signal_fence(__ATOMIC_ACQUIRE);
}

// ---------------- Layer 0: 16 WGs, each owns 16 units (64 gate cols) ----------
// Per step: direct per-lane A-fragment loads from h1[s-1] (no LDS staging),
// Gx fragment add in C-layout, bias folded pre-cst.
__device__ void run_l0(const KParams& p, int sub, float* cst)
{
  const int tid = threadIdx.x;
  const int w = tid >> 6, l = tid & 63, q = l >> 5, lr = l & 31;
  const int mh = w & 1, nh = w >> 1;

  // W1 h-part rows 300..555 -> register B-fragments (reused 512x)
  const int c = nh * 32 + lr;
  const float* Wg = p.W1[c >> 4];
  const int un = sub * 16 + (c & 15);
  const float bias = p.b1[c >> 4][un];
  bf16x8 wf[16];
#pragma unroll
  for (int s = 0; s < 16; ++s)
#pragma unroll
    for (int j = 0; j < 8; ++j) {
      int k = 16 * s + 8 * q + j;
      wf[s][j] = (bf16_t)Wg[(300 + k) * 256 + un];
    }

  float cs[2][2] = {{0.f, 0.f}, {0.f, 0.f}};
  const int arow64 = (mh * 32 + lr) * 64 + q * 2;   // u64 index of lane's A row/khalf

  for (int s = 0; s < 512; ++s) {
    u32 n1 = (s >= H1R) ? (u32)(s - (H1R - 1)) : 0u;  // h1-slab reuse guard
    if (w == 0) waitcond<16, 16>(p.fl0, (u32)s, p.fl1, n1, &p.pflags[s * FP], 1u);
    __syncthreads();

    // direct A-fragment loads from h1[s-1] (each wave independent, no barrier)
    const u64* hp = (const u64*)(p.h1 + ((s + H1R - 1) & (H1R - 1)) * 16384);
    u64 a0[16], a1[16];
#pragma unroll
    for (int s2 = 0; s2 < 16; ++s2) {
      a0[s2] = ald64(hp + arow64 + s2 * 4);
      a1[s2] = ald64(hp + arow64 + s2 * 4 + 1);
    }
    // Gx fragment: lane-linear, 64B contiguous per lane
    const float* gb = p.gx + (size_t)(s % p.R) * 65536u
                    + (size_t)(((sub * 2 + nh) * 2 + mh) * 64 + l) * 16u;
    u64 gv[8];
#pragma unroll
    for (int t = 0; t < 8; ++t) gv[t] = ald64((const u64*)gb + t);

    floatx16 acc;
#pragma unroll
    for (int e = 0; e < 16; ++e) acc[e] = 0.f;
#pragma unroll
    for (int s2 = 0; s2 < 16; ++s2)
      acc = __builtin_amdgcn_mfma_f32_32x32x16_bf16(mk_frag(a0[s2], a1[s2]), wf[s2], acc, 0, 0, 0);

    // add Gx + bias in C-layout (element-exact: producer uses same lane mapping)
#pragma unroll
    for (int t = 0; t < 8; ++t) {
      float2 f2 = u2f2(gv[t]);
      acc[2 * t]     += f2.x + bias;
      acc[2 * t + 1] += f2.y + bias;
    }
#pragma unroll
    for (int e = 0; e < 16; ++e) {
      int ri = (e & 3) + 8 * (e >> 2) + 4 * q;
      cst[(mh * 32 + ri) * 68 + nh * 32 + lr] = acc[e];
    }
    __syncthreads();

    uint16_t* hout = p.h1 + (s & (H1R - 1)) * 16384;
#pragma unroll
    for (int kk = 0; kk < 2; ++kk) {
      int pp = tid + 256 * kk, b = pp >> 3, u2 = (pp & 7) * 2;
      float2 pf = *(float2*)&cst[b * 68 +      u2];
      float2 pi = *(float2*)&cst[b * 68 + 16 + u2];
      float2 pg = *(float2*)&cst[b * 68 + 32 + u2];
      float2 po = *(float2*)&cst[b * 68 + 48 + u2];
      float hv[2];
#pragma unroll
      for (int j = 0; j < 2; ++j) {
        float fj = sigf(j ? pf.y : pf.x);
        float ij = sigf(j ? pi.y : pi.x);
        float gj = tanhf_fast(j ? pg.y : pg.x);
        float oj = sigf(j ? po.y : po.x);
        float cn = fj * cs[kk][j] + ij * gj;
        cs[kk][j] = cn;
        hv[j] = oj * tanhf_fast(cn);
      }
      ast32((u32*)(hout + b * 256 + sub * 16 + u2), pack2(hv[0], hv[1]));
    }
    __syncthreads();                       // drains scoped stores (vmcnt0 + barrier)
    if (tid == 0) {
      ast32(&p.fl0[sub * FP], (u32)(s + 1));    // consumer-polled flag
      ast32(&p.fl0g[sub * FP], (u32)(s + 1));   // producer-polled mirror
    }
  }
}

// ---------------- Layer 1: 32 WGs, each 32 batch rows x 16 units, K=512 -------
// 4 waves = (col-tile nh) x (K-half kh); direct per-lane A-loads from h1/h2;
// partial sums combined via 2-plane cst; bias folded in kh=0 plane.
__device__ void run_l1(const KParams& p, int w2, float* cst)
{
  const int tid = threadIdx.x;
  const int wv = tid >> 6, l = tid & 63, q = l >> 5, lr = l & 31;
  const int nh = wv & 1, kh = wv >> 1;
  const int bh = w2 & 1, sub1 = w2 >> 1;

  const int c = nh * 32 + lr;
  const float* Wg = p.W2[c >> 4];
  const int un = sub1 * 16 + (c & 15);
  const float bias = (kh == 0) ? p.b2[c >> 4][un] : 0.f;
  bf16x8 wf[16];   // this wave's K-half of W2 (z rows kh*256..+256)
#pragma unroll
  for (int s = 0; s < 16; ++s)
#pragma unroll
    for (int j = 0; j < 8; ++j) {
      int k = kh * 256 + s * 16 + q * 8 + j;
      wf[s][j] = (bf16_t)Wg[k * 256 + un];
    }

  float cs2[2] = {0.f, 0.f};   // c-state: thread owns (b = tid>>3, units u2,u2+1)
  const int cb = tid >> 3, cu = (tid & 7) * 2;
  const int arow64 = (bh * 32 + lr) * 64 + q * 2;

  for (int s = 0; s < 512; ++s) {
    // merged wait: all 32 L1 peers done s-1 (h2 ready) AND all 16 L0 done s (h1 ready)
    if (wv == 0) waitcond<32, 16>(p.fl1, (u32)s, p.fl0, (u32)(s + 1), p.fl0, 0u);
    __syncthreads();

    // direct A-fragment loads: kh=0 -> h1[s], kh=1 -> h2[s-1]
    const u64* hp = (kh == 0)
        ? (const u64*)(p.h1 + (s & (H1R - 1)) * 16384)
        : (const u64*)(p.h2 + ((s + 1) & 1) * 16384);
    u64 a0[16], a1[16];
#pragma unroll
    for (int s2 = 0; s2 < 16; ++s2) {
      a0[s2] = ald64(hp + arow64 + s2 * 4);
      a1[s2] = ald64(hp + arow64 + s2 * 4 + 1);
    }

    floatx16 acc;
#pragma unroll
    for (int e = 0; e < 16; ++e) acc[e] = 0.f;
#pragma unroll
    for (int s2 = 0; s2 < 16; ++s2)
      acc = __builtin_amdgcn_mfma_f32_32x32x16_bf16(mk_frag(a0[s2], a1[s2]), wf[s2], acc, 0, 0, 0);
#pragma unroll
    for (int e = 0; e < 16; ++e) {
      int ri = (e & 3) + 8 * (e >> 2) + 4 * q;
      cst[kh * 2176 + ri * 68 + nh * 32 + lr] = acc[e] + bias;
    }
    __syncthreads();

    // cell: sum the two K-half planes
    uint16_t* hout = p.h2 + (s & 1) * 16384;
    {
      float2 pf = *(float2*)&cst[cb * 68 +      cu];
      float2 pi = *(float2*)&cst[cb * 68 + 16 + cu];
      float2 pg = *(float2*)&cst[cb * 68 + 32 + cu];
      float2 po = *(float2*)&cst[cb * 68 + 48 + cu];
      float2 qf = *(float2*)&cst[2176 + cb * 68 +      cu];
      float2 qi = *(float2*)&cst[2176 + cb * 68 + 16 + cu];
      float2 qg = *(float2*)&cst[2176 + cb * 68 + 32 + cu];
      float2 qo = *(float2*)&cst[2176 + cb * 68 + 48 + cu];
      float hv[2];
#pragma unroll
      for (int j = 0; j < 2; ++j) {
        float fj = sigf(j ? pf.y + qf.y : pf.x + qf.x);
        float ij = sigf(j ? pi.y + qi.y : pi.x + qi.x);
        float gj = tanhf_fast(j ? pg.y + qg.y : pg.x + qg.x);
        float oj = sigf(j ? po.y + qo.y : po.x + qo.x);
        float cn = fj * cs2[j] + ij * gj;
        cs2[j] = cn;
        hv[j] = oj * tanhf_fast(cn);
      }
      ast32((u32*)(hout + (bh * 32 + cb) * 256 + sub1 * 16 + cu), pack2(hv[0], hv[1]));
    }
    __syncthreads();
    if (tid == 0) ast32(&p.fl1[w2 * FP], (u32)(s + 1));
  }

  // ---- dense head part 1: 4 cols of d = relu(h2_last @ Wd + bd) -------------
  if (wv == 0) waitcond<32, 0>(p.fl1, 512u, p.fl1, 0u, p.fl1, 0u);
  __syncthreads();
  {
    const u64* hp = (const u64*)(p.h2 + 16384);   // h2[511] slab 1
    u64 tmp[16];
#pragma unroll
    for (int t = 0; t < 16; ++t) tmp[t] = ald64(hp + tid + 256 * t);
#pragma unroll
    for (int t = 0; t < 16; ++t) {
      int i = tid + 256 * t, b = i >> 6, cc = i & 63;
      *(u64*)((char*)cst + b * 520 + cc * 8) = tmp[t];
    }
  }
  __syncthreads();
  {
    int b = tid >> 2, cc = w2 * 4 + (tid & 3);
    const bf16_t* hrow = (const bf16_t*)((char*)cst + b * 520);
    float a = p.bd[cc];
#pragma unroll 8
    for (int k = 0; k < 256; ++k) a += (float)hrow[k] * p.Wd[k * 128 + cc];
    ast32((u32*)&p.dstage[b * 128 + cc], __builtin_bit_cast(u32, fmaxf(a, 0.f)));
  }
  __syncthreads();
  if (tid == 0) ast32(&p.fl1[w2 * FP], 513u);

  // ---- final: out = sigmoid(d @ Wout + bout), by L1 WG 0 --------------------
  if (w2 == 0) {
    if (wv == 0) waitcond<32, 0>(p.fl1, 513u, p.fl1, 0u, p.fl1, 0u);
    __syncthreads();
    if (tid < 64) {
      float a = p.bout[0];
#pragma unroll 8
      for (int cc = 0; cc < 128; ++cc) {
        u32 dv = ald32((u32*)&p.dstage[tid * 128 + cc]);
        a += __builtin_bit_cast(float, dv) * p.Wout[cc];
      }
      p.out[tid] = sigf(a);
    }
  }
}

// ---------------- Gx producers: Gx[s] = x_s @ W1x, K=300 (pad 320) -------------
// Output stored lane-linear: [ct][mh][lane][e] fp32 -> consumer reads 64B/lane.
__device__ void run_prod(const KParams& p, int pw, char* smem)
{
  const int tid = threadIdx.x;
  const int w = tid >> 6, l = tid & 63, q = l >> 5, lr = l & 31;
  const int mh = w & 1, chalf = w >> 1;
  const int R = p.R;

  for (int jj = 0; jj < 512 / NPROD; ++jj) {
    const int s = pw + NPROD * jj;
    if (s >= R) {  // ring throttle via producer-only mirror (off the hot fl0 lines)
      if (w == 0) waitg16(p.fl0g, (u32)(s - R + 1));
    }
    __syncthreads();
    {
      int b = tid >> 2, qq = tid & 3;
      int tokv = p.tok[b * 512 + s];
      const float4* src = (const float4*)(p.emb + (size_t)tokv * 300);
      char* dst = smem + b * 656;
      for (int j2 = qq; j2 < 75; j2 += 4) {
        float4 v = src[j2];
        *(u32*)(dst + 8 * j2)     = pack2(v.x, v.y);
        *(u32*)(dst + 8 * j2 + 4) = pack2(v.z, v.w);
      }
      for (int i = tid; i < 640; i += 256) {
        int bb = i / 10, cc2 = i % 10;
        *(u32*)(smem + bb * 656 + 600 + cc2 * 4) = 0u;
      }
    }
    __syncthreads();

    bf16x8 afr[20];
    const char* arow = smem + (mh * 32 + lr) * 656 + q * 16;
#pragma unroll
    for (int kt = 0; kt < 20; ++kt) afr[kt] = *(const bf16x8*)(arow + 32 * kt);

    float* slab = p.gx + (size_t)(s % R) * 65536u;
    for (int c2 = 0; c2 < 16; ++c2) {
      int ct = chalf * 16 + c2;
      int n = ct * 32 + lr;
      floatx16 acc;
#pragma unroll
      for (int e = 0; e < 16; ++e) acc[e] = 0.f;
#pragma unroll
      for (int kt = 0; kt < 20; ++kt) {
        bf16x8 bf = ((const bf16x8*)p.w1bf)[(kt * 1024 + n) * 2 + q];
        acc = __builtin_amdgcn_mfma_f32_32x32x16_bf16(afr[kt], bf, acc, 0, 0, 0);
      }
      u64* gout = (u64*)(slab + (size_t)((ct * 2 + mh) * 64 + l) * 16u);
#pragma unroll
      for (int t = 0; t < 8; ++t) ast64(gout + t, f22u(acc[2 * t], acc[2 * t + 1]));
    }
    __syncthreads();                    // drains Gx scoped stores
    if (tid == 0) ast32(&p.pflags[s * FP], 1u);
  }
}

__global__ __launch_bounds__(256, 1) void lstm_main(KParams p)
{
  __shared__ __align__(16) char smem[64 * 656];   // producer stage buf / head stage
  __shared__ float cst[4352];                     // L0: [64][68]; L1: [2][32][68]
  const int wg = blockIdx.x;
  if (wg < 16)       run_l0(p, wg, cst);
  else if (wg < 48)  run_l1(p, wg - 16, cst);
  else               run_prod(p, wg - 48, smem);
}

// One-time: W1 x-part (rows 0..299, zero-pad to 320) -> bf16 fragment order.
__global__ void prep_w(KParams p) {
  int idx = blockIdx.x * 256 + threadIdx.x;
  if (idx >= 20 * 1024 * 16) return;
  int kk = idx & 15, n = (idx >> 4) & 1023, kt = idx >> 14;
  int k = kt * 16 + kk;
  int g = (n >> 4) & 3, su = n >> 6, u = n & 15;
  float v = (k < 300) ? p.W1[g][k * 256 + su * 16 + u] : 0.f;
  p.w1bf[idx] = (bf16_t)v;
}

// Zero h rings + all flags (ws is re-poisoned 0xAA before every launch)
__global__ void init_ws(u32* ws32) {
  int i = blockIdx.x * 256 + threadIdx.x;
  if (i < 165888) ws32[i] = 0u;   // [0, 663552): h1, h2, fl0, fl1, fl0g, pflags
}

extern "C" void kernel_launch(void* const* d_in, const int* in_sizes, int n_in,
                              void* d_out, int out_size, void* d_ws, size_t ws_size,
                              hipStream_t stream)
{
  KParams p;
  p.tok = (const int*)d_in[0];
  p.emb = (const float*)d_in[1];
  for (int g = 0; g < 4; ++g) {
    p.W1[g] = (const float*)d_in[2 + 2 * g];
    p.b1[g] = (const float*)d_in[3 + 2 * g];
    p.W2[g] = (const float*)d_in[10 + 2 * g];
    p.b2[g] = (const float*)d_in[11 + 2 * g];
  }
  p.Wd   = (const float*)d_in[18];
  p.bd   = (const float*)d_in[19];
  p.Wout = (const float*)d_in[20];
  p.bout = (const float*)d_in[21];
  p.out  = (float*)d_out;

  char* ws = (char*)d_ws;
  p.h1     = (uint16_t*)ws;               // 16 x 32768 B  -> 524288
  p.h2     = (uint16_t*)(ws + 524288);    // 2 x 32768 B   -> 589824
  p.fl0    = (u32*)(ws + 589824);         // 16 x 128 B    -> 591872
  p.fl1    = (u32*)(ws + 591872);         // 32 x 128 B    -> 595968
  p.fl0g   = (u32*)(ws + 595968);         // 16 x 128 B    -> 598016
  p.pflags = (u32*)(ws + 598016);         // 512 x 128 B   -> 663552
  p.dstage = (float*)(ws + 663552);       // 32768 B       -> 696320
  p.w1bf   = (bf16_t*)(ws + 696320);      // 655360 B      -> 1351680
  p.gx     = (float*)(ws + 1351680);      // ring: R x 262144 B

  long avail = (long)ws_size - 1351680L;
  int R = (int)(avail / 262144L);
  if (R > 64) R = 64;
  if (R < 1)  R = 1;
  p.R = R;

  hipLaunchKernelGGL(init_ws, dim3(648), dim3(256), 0, stream, (u32*)d_ws);
  hipLaunchKernelGGL(prep_w, dim3(1280), dim3(256), 0, stream, p);
  hipLaunchKernelGGL(lstm_main, dim3(16 + 32 + NPROD), dim3(256), 0, stream, p);
}